// Round 1
// baseline (210.803 us; speedup 1.0000x reference)
//
#include <hip/hip_runtime.h>

#define N_TOK 131072
#define TILE 64
#define NT_MAX 2064          // N_TOK/TILE + 16 tasks worth of padding tiles
#define XS 136               // X row stride (bf16 elems): 128 + 8 pad
#define HS 264               // H row stride (bf16 elems): 256 + 8 pad

typedef __attribute__((ext_vector_type(8))) short s8v;
typedef __attribute__((ext_vector_type(4))) float f4v;
typedef unsigned short ushort_t;

__device__ __forceinline__ unsigned short f2bf(float x) {
    union { float f; unsigned u; } v; v.f = x;
    unsigned r = v.u + 0x7fffu + ((v.u >> 16) & 1u);   // RNE
    return (unsigned short)(r >> 16);
}

__device__ __forceinline__ float tanh_fast(float x) {
    float e = __expf(2.0f * x);
    return 1.0f - 2.0f / (e + 1.0f);
}

// ---------------------------------------------------------------- prep weights
// Repack W[c][k][n] (f32) -> bf16 in MFMA-B-fragment order:
// frag(ntile=n>>4, ktile=k>>5): lane = (n&15) | (((k&31)>>3)<<4), elem j = k&7
// dst elem idx = (((n>>4)*(K>>5) + (k>>5))*64 + lane)*8 + (k&7)
__global__ void prep_kernel(const float* __restrict__ W0, const float* __restrict__ W1,
                            const float* __restrict__ W2,
                            ushort_t* __restrict__ W0p, ushort_t* __restrict__ W1p,
                            ushort_t* __restrict__ W2p) {
    int i = blockIdx.x * 256 + threadIdx.x;   // 458752 total
    const float* src; ushort_t* dst; int K, N, rem;
    if (i < 131072)      { src = W0; dst = W0p; K = 128; N = 256; rem = i; }
    else if (i < 393216) { src = W1; dst = W1p; K = 256; N = 256; rem = i - 131072; }
    else if (i < 458752) { src = W2; dst = W2p; K = 256; N = 64;  rem = i - 393216; }
    else return;
    int per = K * N;
    int c = rem / per, kn = rem % per;
    int k = kn / N, n = kn % N;
    float v = src[rem];
    int lane = (n & 15) | (((k & 31) >> 3) << 4);
    int didx = ((((n >> 4) * (K >> 5) + (k >> 5)) * 64 + lane) << 3) + (k & 7);
    dst[c * per + didx] = f2bf(v);
}

// ---------------------------------------------------------------- sort by task
__global__ void hist_kernel(const int* __restrict__ task, int* __restrict__ blockCounts) {
    __shared__ int cnt[16];
    int t = threadIdx.x;
    if (t < 16) cnt[t] = 0;
    __syncthreads();
    atomicAdd(&cnt[task[blockIdx.x * 256 + t]], 1);
    __syncthreads();
    if (t < 16) blockCounts[blockIdx.x * 16 + t] = cnt[t];
}

__global__ void scan_kernel(const int* __restrict__ blockCounts, int* __restrict__ cur,
                            int* __restrict__ tileTask, int* __restrict__ nT) {
    __shared__ int cnt[16];
    __shared__ int tbase[17];
    int t = threadIdx.x;
    if (t < 16) {
        int s = 0;
        for (int b = 0; b < 512; b++) s += blockCounts[b * 16 + t];
        cnt[t] = s;
    }
    __syncthreads();
    if (t == 0) {
        int tok = 0, tile = 0;
        for (int k = 0; k < 16; k++) {
            cur[k] = tok;                      // token write cursor (tile-aligned base)
            int ntk = (cnt[k] + TILE - 1) / TILE;
            tbase[k] = tile;
            tok += ntk * TILE;
            tile += ntk;
        }
        tbase[16] = tile;
        nT[0] = tile;
    }
    __syncthreads();
    if (t < 16) {
        for (int i = tbase[t]; i < tbase[t + 1]; i++) tileTask[i] = t;
    }
}

__global__ void scatter_kernel(const int* __restrict__ task, int* __restrict__ cur,
                               int* __restrict__ perm) {
    __shared__ int cnt[16];
    __shared__ int basesh[16];
    int t = threadIdx.x;
    if (t < 16) cnt[t] = 0;
    __syncthreads();
    int i = blockIdx.x * 256 + t;
    int tk = task[i];
    int my = atomicAdd(&cnt[tk], 1);
    __syncthreads();
    if (t < 16) basesh[t] = atomicAdd(&cur[t], cnt[t]);
    __syncthreads();
    perm[basesh[tk] + my] = i;
}

// ---------------------------------------------------------------- fused MLP
__launch_bounds__(256, 2)
__global__ void mlp_kernel(const float* __restrict__ x_in,
                           const int* __restrict__ cmap,
                           const float* __restrict__ b0,
                           const float* __restrict__ b1,
                           const float* __restrict__ b2,
                           const ushort_t* __restrict__ W0p,
                           const ushort_t* __restrict__ W1p,
                           const ushort_t* __restrict__ W2p,
                           const int* __restrict__ tileTask,
                           const int* __restrict__ nTp,
                           const int* __restrict__ perm,
                           float* __restrict__ out) {
    __shared__ ushort_t bufA[TILE * HS];   // X (stride XS) then H2 (stride HS)
    __shared__ ushort_t bufB[TILE * HS];   // H1 (stride HS)
    __shared__ int toks[TILE];

    int b = blockIdx.x;
    if (b >= nTp[0]) return;
    int t = threadIdx.x;
    int task = tileTask[b];
    int c0 = cmap[task], c1 = cmap[16 + task], c2 = cmap[32 + task];
    if (t < TILE) toks[t] = perm[b * TILE + t];
    __syncthreads();

    // ---- stage X: gather rows, f32 -> bf16, into bufA (stride XS)
    {
        int r = t >> 2, q = t & 3;
        unsigned tok = (unsigned)toks[r];
        float4 v[8];
        if (tok < (unsigned)N_TOK) {
            const float4* src = reinterpret_cast<const float4*>(x_in) + (size_t)tok * 32 + q * 8;
#pragma unroll
            for (int i = 0; i < 8; i++) v[i] = src[i];
        } else {
#pragma unroll
            for (int i = 0; i < 8; i++) v[i] = make_float4(0.f, 0.f, 0.f, 0.f);
        }
        ushort_t* dst = &bufA[r * XS + q * 32];
#pragma unroll
        for (int i = 0; i < 4; i++) {
            float4 va = v[2 * i], vb = v[2 * i + 1];
            s8v pk;
            pk[0] = (short)f2bf(va.x); pk[1] = (short)f2bf(va.y);
            pk[2] = (short)f2bf(va.z); pk[3] = (short)f2bf(va.w);
            pk[4] = (short)f2bf(vb.x); pk[5] = (short)f2bf(vb.y);
            pk[6] = (short)f2bf(vb.z); pk[7] = (short)f2bf(vb.w);
            *reinterpret_cast<s8v*>(dst + i * 8) = pk;
        }
    }
    __syncthreads();

    int w = t >> 6;
    int lane = t & 63;
    int l15 = lane & 15, lq = lane >> 4;

    // ---- Layer 0: X[64,128] @ W0[c0] -> tanh -> H1 (bufB)
    {
        f4v acc[4][4];
#pragma unroll
        for (int mt = 0; mt < 4; mt++)
#pragma unroll
            for (int nt = 0; nt < 4; nt++) { f4v z = {0.f, 0.f, 0.f, 0.f}; acc[mt][nt] = z; }
        const ushort_t* Wc = W0p + (size_t)c0 * 32768;
#pragma unroll
        for (int kt = 0; kt < 4; kt++) {
            s8v a[4];
#pragma unroll
            for (int mt = 0; mt < 4; mt++)
                a[mt] = *reinterpret_cast<const s8v*>(&bufA[(mt * 16 + l15) * XS + kt * 32 + lq * 8]);
            s8v bb[4];
#pragma unroll
            for (int nt = 0; nt < 4; nt++) {
                int n16 = w * 4 + nt;
                bb[nt] = *reinterpret_cast<const s8v*>(Wc + (((n16 * 4 + kt) * 64 + lane) << 3));
            }
#pragma unroll
            for (int mt = 0; mt < 4; mt++)
#pragma unroll
                for (int nt = 0; nt < 4; nt++)
                    acc[mt][nt] = __builtin_amdgcn_mfma_f32_16x16x32_bf16(a[mt], bb[nt], acc[mt][nt], 0, 0, 0);
        }
        float bias[4];
#pragma unroll
        for (int nt = 0; nt < 4; nt++) bias[nt] = b0[c0 * 256 + w * 64 + nt * 16 + l15];
#pragma unroll
        for (int mt = 0; mt < 4; mt++)
#pragma unroll
            for (int nt = 0; nt < 4; nt++)
#pragma unroll
                for (int rg = 0; rg < 4; rg++) {
                    float v = tanh_fast(acc[mt][nt][rg] + bias[nt]);
                    bufB[(mt * 16 + lq * 4 + rg) * HS + w * 64 + nt * 16 + l15] = f2bf(v);
                }
    }
    __syncthreads();

    // ---- Layer 1: H1[64,256] @ W1[c1] -> tanh -> H2 (bufA, X is dead)
    {
        f4v acc[4][4];
#pragma unroll
        for (int mt = 0; mt < 4; mt++)
#pragma unroll
            for (int nt = 0; nt < 4; nt++) { f4v z = {0.f, 0.f, 0.f, 0.f}; acc[mt][nt] = z; }
        const ushort_t* Wc = W1p + (size_t)c1 * 65536;
#pragma unroll
        for (int kt = 0; kt < 8; kt++) {
            s8v a[4];
#pragma unroll
            for (int mt = 0; mt < 4; mt++)
                a[mt] = *reinterpret_cast<const s8v*>(&bufB[(mt * 16 + l15) * HS + kt * 32 + lq * 8]);
            s8v bb[4];
#pragma unroll
            for (int nt = 0; nt < 4; nt++) {
                int n16 = w * 4 + nt;
                bb[nt] = *reinterpret_cast<const s8v*>(Wc + (((n16 * 8 + kt) * 64 + lane) << 3));
            }
#pragma unroll
            for (int mt = 0; mt < 4; mt++)
#pragma unroll
                for (int nt = 0; nt < 4; nt++)
                    acc[mt][nt] = __builtin_amdgcn_mfma_f32_16x16x32_bf16(a[mt], bb[nt], acc[mt][nt], 0, 0, 0);
        }
        float bias[4];
#pragma unroll
        for (int nt = 0; nt < 4; nt++) bias[nt] = b1[c1 * 256 + w * 64 + nt * 16 + l15];
#pragma unroll
        for (int mt = 0; mt < 4; mt++)
#pragma unroll
            for (int nt = 0; nt < 4; nt++)
#pragma unroll
                for (int rg = 0; rg < 4; rg++) {
                    float v = tanh_fast(acc[mt][nt][rg] + bias[nt]);
                    bufA[(mt * 16 + lq * 4 + rg) * HS + w * 64 + nt * 16 + l15] = f2bf(v);
                }
    }
    __syncthreads();

    // ---- Layer 2: H2[64,256] @ W2[c2] -> out (scatter rows by perm)
    {
        f4v acc[4];
#pragma unroll
        for (int mt = 0; mt < 4; mt++) { f4v z = {0.f, 0.f, 0.f, 0.f}; acc[mt] = z; }
        const ushort_t* Wc = W2p + (size_t)c2 * 16384;
#pragma unroll
        for (int kt = 0; kt < 8; kt++) {
            s8v a[4];
#pragma unroll
            for (int mt = 0; mt < 4; mt++)
                a[mt] = *reinterpret_cast<const s8v*>(&bufA[(mt * 16 + l15) * HS + kt * 32 + lq * 8]);
            s8v bb = *reinterpret_cast<const s8v*>(Wc + ((((w * 8) + kt) * 64 + lane) << 3));
#pragma unroll
            for (int mt = 0; mt < 4; mt++)
                acc[mt] = __builtin_amdgcn_mfma_f32_16x16x32_bf16(a[mt], bb, acc[mt], 0, 0, 0);
        }
        float bias = b2[c2 * 64 + w * 16 + l15];
#pragma unroll
        for (int mt = 0; mt < 4; mt++)
#pragma unroll
            for (int rg = 0; rg < 4; rg++) {
                int row = mt * 16 + lq * 4 + rg;
                unsigned tok = (unsigned)toks[row];
                if (tok < (unsigned)N_TOK)
                    out[(size_t)tok * 64 + w * 16 + l15] = acc[mt][rg] + bias;
            }
    }
}

// ---------------------------------------------------------------- launch
extern "C" void kernel_launch(void* const* d_in, const int* in_sizes, int n_in,
                              void* d_out, int out_size, void* d_ws, size_t ws_size,
                              hipStream_t stream) {
    const float* inputs = (const float*)d_in[0];
    const int*   task   = (const int*)d_in[1];
    const int*   cmap   = (const int*)d_in[2];
    const float* W0     = (const float*)d_in[3];
    const float* b0     = (const float*)d_in[4];
    const float* W1     = (const float*)d_in[5];
    const float* b1     = (const float*)d_in[6];
    const float* W2     = (const float*)d_in[7];
    const float* b2     = (const float*)d_in[8];
    float* out = (float*)d_out;

    char* ws = (char*)d_ws;
    int* blockCounts = (int*)(ws + 0);            // 512*16*4 = 32768 B
    int* cur         = (int*)(ws + 32768);        // 16*4 B
    int* nT          = (int*)(ws + 32832);        // 4 B
    int* tileTask    = (int*)(ws + 33024);        // 2064*4 = 8256 B
    int* perm        = (int*)(ws + 41472);        // 132096*4 = 528384 B
    ushort_t* W0p    = (ushort_t*)(ws + 570368);  // 262144 B
    ushort_t* W1p    = (ushort_t*)(ws + 832512);  // 524288 B
    ushort_t* W2p    = (ushort_t*)(ws + 1356800); // 131072 B -> total ~1.42 MB

    prep_kernel<<<1792, 256, 0, stream>>>(W0, W1, W2, W0p, W1p, W2p);
    hist_kernel<<<512, 256, 0, stream>>>(task, blockCounts);
    scan_kernel<<<1, 256, 0, stream>>>(blockCounts, cur, tileTask, nT);
    scatter_kernel<<<512, 256, 0, stream>>>(task, cur, perm);
    mlp_kernel<<<NT_MAX, 256, 0, stream>>>(inputs, cmap, b0, b1, b2,
                                           W0p, W1p, W2p, tileTask, nT, perm, out);
}

// Round 2
// 188.693 us; speedup vs baseline: 1.1172x; 1.1172x over previous
//
#include <hip/hip_runtime.h>

#define N_TOK 131072
#define TILE 64
#define NT_MAX 2064          // N_TOK/TILE + 16 tasks worth of padding tiles
#define XS 136               // X row stride (bf16 elems): 128 + 8 pad
#define HS 264               // H row stride (bf16 elems): 256 + 8 pad
#define SCR_S 68             // f32 scratch row stride (dwords): 64 + 4 pad

typedef __attribute__((ext_vector_type(8))) short s8v;
typedef __attribute__((ext_vector_type(4))) float f4v;
typedef unsigned short ushort_t;

__device__ __forceinline__ unsigned short f2bf(float x) {
    union { float f; unsigned u; } v; v.f = x;
    unsigned r = v.u + 0x7fffu + ((v.u >> 16) & 1u);   // RNE
    return (unsigned short)(r >> 16);
}

__device__ __forceinline__ float tanh_fast(float x) {
    float e = __expf(2.0f * x);
    return 1.0f - 2.0f / (e + 1.0f);
}

// ---------------------------------------------------------------- prep weights
// One thread per 8-elem B-fragment slice: 16B coalesced write, 8 gathered reads.
// Fragment order (as consumed by mlp): r = (ntile*(K>>5)+kt)*64 + lane,
// lane = (n&15) | (((k&31)>>3)<<4), elem j = k&7. dst elem = (c*fpc + r)*8 + j.
__global__ void prep_kernel(const float* __restrict__ W0, const float* __restrict__ W1,
                            const float* __restrict__ W2,
                            ushort_t* __restrict__ W0p, ushort_t* __restrict__ W1p,
                            ushort_t* __restrict__ W2p) {
    int f = blockIdx.x * 256 + threadIdx.x;   // 57344 total fragments
    const float* src; ushort_t* dst; int K, N;
    if (f < 16384)      { src = W0; dst = W0p; K = 128; N = 256; }
    else if (f < 49152) { src = W1; dst = W1p; K = 256; N = 256; f -= 16384; }
    else if (f < 57344) { src = W2; dst = W2p; K = 256; N = 64;  f -= 49152; }
    else return;
    int fpc = (N >> 4) * (K >> 5) * 64;       // fragments per copy
    int c = f / fpc, r = f % fpc;
    int lane = r & 63;
    int kt = (r >> 6) % (K >> 5);
    int ntile = (r >> 6) / (K >> 5);
    int n = ntile * 16 + (lane & 15);
    int kbase = kt * 32 + (lane >> 4) * 8;
    const float* s = src + (size_t)c * K * N + (size_t)kbase * N + n;
    s8v pk;
#pragma unroll
    for (int j = 0; j < 8; j++) pk[j] = (short)f2bf(s[(size_t)j * N]);
    *reinterpret_cast<s8v*>(dst + ((size_t)(c * fpc + r) << 3)) = pk;
}

// ---------------------------------------------------------------- sort by task
__global__ void hist_kernel(const int* __restrict__ task, int* __restrict__ blockCounts) {
    __shared__ int cnt[16];
    int t = threadIdx.x;
    if (t < 16) cnt[t] = 0;
    __syncthreads();
    int base = blockIdx.x * 2048 + t;
#pragma unroll
    for (int i = 0; i < 8; i++) atomicAdd(&cnt[task[base + i * 256]], 1);
    __syncthreads();
    if (t < 16) blockCounts[blockIdx.x * 16 + t] = cnt[t];
}

__global__ void scan_kernel(const int* __restrict__ blockCounts, int* __restrict__ cur,
                            int* __restrict__ tileTask, int* __restrict__ nT) {
    __shared__ int cnt[16];
    __shared__ int tbase[17];
    int t = threadIdx.x;
    if (t < 16) {
        int s = 0;
#pragma unroll
        for (int b = 0; b < 64; b++) s += blockCounts[b * 16 + t];
        cnt[t] = s;
    }
    __syncthreads();
    if (t == 0) {
        int tok = 0, tile = 0;
        for (int k = 0; k < 16; k++) {
            cur[k] = tok;                      // token write cursor (tile-aligned base)
            int ntk = (cnt[k] + TILE - 1) / TILE;
            tbase[k] = tile;
            tok += ntk * TILE;
            tile += ntk;
        }
        tbase[16] = tile;
        nT[0] = tile;
    }
    __syncthreads();
    for (int i = t; i < NT_MAX; i += 256) {
        int tk = 0;
        if (i < tbase[16]) {
#pragma unroll
            for (int k = 0; k < 16; k++) if (i >= tbase[k]) tk = k;
        }
        tileTask[i] = tk;
    }
}

__global__ void scatter_kernel(const int* __restrict__ task, int* __restrict__ cur,
                               int* __restrict__ perm) {
    __shared__ int cnt[16];
    __shared__ int basesh[16];
    int t = threadIdx.x;
    if (t < 16) cnt[t] = 0;
    __syncthreads();
    int tk[8], my[8];
#pragma unroll
    for (int i = 0; i < 8; i++) {
        int idx = blockIdx.x * 2048 + i * 256 + t;
        tk[i] = task[idx];
        my[i] = atomicAdd(&cnt[tk[i]], 1);
    }
    __syncthreads();
    if (t < 16) basesh[t] = atomicAdd(&cur[t], cnt[t]);
    __syncthreads();
#pragma unroll
    for (int i = 0; i < 8; i++) {
        int idx = blockIdx.x * 2048 + i * 256 + t;
        perm[basesh[tk[i]] + my[i]] = idx;
    }
}

// ---------------------------------------------------------------- fused MLP
// 512 threads = 8 waves/block; 68KB LDS -> 2 blocks/CU -> 16 waves/CU (50% cap).
__launch_bounds__(512, 4)
__global__ void mlp_kernel(const float* __restrict__ x_in,
                           const int* __restrict__ cmap,
                           const float* __restrict__ b0,
                           const float* __restrict__ b1,
                           const float* __restrict__ b2,
                           const ushort_t* __restrict__ W0p,
                           const ushort_t* __restrict__ W1p,
                           const ushort_t* __restrict__ W2p,
                           const int* __restrict__ tileTask,
                           const int* __restrict__ nTp,
                           const int* __restrict__ perm,
                           float* __restrict__ out) {
    __shared__ __align__(16) ushort_t bufA[TILE * HS];   // X (stride XS) then H2 (stride HS)
    __shared__ __align__(16) ushort_t bufB[TILE * HS];   // H1 (stride HS); f32 scratch in layer2
    __shared__ int toks[TILE];

    int b = blockIdx.x;
    if (b >= nTp[0]) return;
    int t = threadIdx.x;
    int task = tileTask[b];
    int c0 = cmap[task], c1 = cmap[16 + task], c2 = cmap[32 + task];
    if (t < TILE) toks[t] = perm[b * TILE + t];
    __syncthreads();

    // ---- stage X: gather rows, f32 -> bf16, into bufA (stride XS)
    {
        int r = t >> 3, q = t & 7;            // 8 threads/row, 16 floats each
        unsigned tok = (unsigned)toks[r];
        float4 v[4];
        if (tok < (unsigned)N_TOK) {
            const float4* src = reinterpret_cast<const float4*>(x_in) + (size_t)tok * 32 + q * 4;
#pragma unroll
            for (int i = 0; i < 4; i++) v[i] = src[i];
        } else {
#pragma unroll
            for (int i = 0; i < 4; i++) v[i] = make_float4(0.f, 0.f, 0.f, 0.f);
        }
        ushort_t* dst = &bufA[r * XS + q * 16];
#pragma unroll
        for (int i = 0; i < 2; i++) {
            float4 va = v[2 * i], vb = v[2 * i + 1];
            s8v pk;
            pk[0] = (short)f2bf(va.x); pk[1] = (short)f2bf(va.y);
            pk[2] = (short)f2bf(va.z); pk[3] = (short)f2bf(va.w);
            pk[4] = (short)f2bf(vb.x); pk[5] = (short)f2bf(vb.y);
            pk[6] = (short)f2bf(vb.z); pk[7] = (short)f2bf(vb.w);
            *reinterpret_cast<s8v*>(dst + i * 8) = pk;
        }
    }
    __syncthreads();

    int w = t >> 6;                 // wave 0..7
    int lane = t & 63;
    int l15 = lane & 15, lq = lane >> 4;

    // ---- Layer 0: X[64,128] @ W0[c0] -> tanh -> H1 (bufB). Wave w: cols [w*32, w*32+32)
    {
        f4v acc[4][2];
#pragma unroll
        for (int mt = 0; mt < 4; mt++)
#pragma unroll
            for (int nt = 0; nt < 2; nt++) { f4v z = {0.f, 0.f, 0.f, 0.f}; acc[mt][nt] = z; }
        const ushort_t* Wc = W0p + (size_t)c0 * 32768;
#pragma unroll
        for (int kt = 0; kt < 4; kt++) {
            s8v a[4];
#pragma unroll
            for (int mt = 0; mt < 4; mt++)
                a[mt] = *reinterpret_cast<const s8v*>(&bufA[(mt * 16 + l15) * XS + kt * 32 + lq * 8]);
            s8v bb[2];
#pragma unroll
            for (int nt = 0; nt < 2; nt++) {
                int n16 = w * 2 + nt;
                bb[nt] = *reinterpret_cast<const s8v*>(Wc + (((n16 * 4 + kt) * 64 + lane) << 3));
            }
#pragma unroll
            for (int mt = 0; mt < 4; mt++)
#pragma unroll
                for (int nt = 0; nt < 2; nt++)
                    acc[mt][nt] = __builtin_amdgcn_mfma_f32_16x16x32_bf16(a[mt], bb[nt], acc[mt][nt], 0, 0, 0);
        }
        float bias[2];
#pragma unroll
        for (int nt = 0; nt < 2; nt++) bias[nt] = b0[c0 * 256 + w * 32 + nt * 16 + l15];
#pragma unroll
        for (int mt = 0; mt < 4; mt++)
#pragma unroll
            for (int nt = 0; nt < 2; nt++)
#pragma unroll
                for (int rg = 0; rg < 4; rg++) {
                    float v = tanh_fast(acc[mt][nt][rg] + bias[nt]);
                    bufB[(mt * 16 + lq * 4 + rg) * HS + w * 32 + nt * 16 + l15] = f2bf(v);
                }
    }
    __syncthreads();

    // ---- Layer 1: H1[64,256] @ W1[c1] -> tanh -> H2 (bufA; X dead)
    {
        f4v acc[4][2];
#pragma unroll
        for (int mt = 0; mt < 4; mt++)
#pragma unroll
            for (int nt = 0; nt < 2; nt++) { f4v z = {0.f, 0.f, 0.f, 0.f}; acc[mt][nt] = z; }
        const ushort_t* Wc = W1p + (size_t)c1 * 65536;
#pragma unroll
        for (int kt = 0; kt < 8; kt++) {
            s8v a[4];
#pragma unroll
            for (int mt = 0; mt < 4; mt++)
                a[mt] = *reinterpret_cast<const s8v*>(&bufB[(mt * 16 + l15) * HS + kt * 32 + lq * 8]);
            s8v bb[2];
#pragma unroll
            for (int nt = 0; nt < 2; nt++) {
                int n16 = w * 2 + nt;
                bb[nt] = *reinterpret_cast<const s8v*>(Wc + (((n16 * 8 + kt) * 64 + lane) << 3));
            }
#pragma unroll
            for (int mt = 0; mt < 4; mt++)
#pragma unroll
                for (int nt = 0; nt < 2; nt++)
                    acc[mt][nt] = __builtin_amdgcn_mfma_f32_16x16x32_bf16(a[mt], bb[nt], acc[mt][nt], 0, 0, 0);
        }
        float bias[2];
#pragma unroll
        for (int nt = 0; nt < 2; nt++) bias[nt] = b1[c1 * 256 + w * 32 + nt * 16 + l15];
#pragma unroll
        for (int mt = 0; mt < 4; mt++)
#pragma unroll
            for (int nt = 0; nt < 2; nt++)
#pragma unroll
                for (int rg = 0; rg < 4; rg++) {
                    float v = tanh_fast(acc[mt][nt][rg] + bias[nt]);
                    bufA[(mt * 16 + lq * 4 + rg) * HS + w * 32 + nt * 16 + l15] = f2bf(v);
                }
    }
    __syncthreads();

    // ---- Layer 2: H2[64,256] @ W2[c2] -> out. All 8 waves: n16 = w&3, k-half = w>>2.
    {
        int n16 = w & 3, khalf = w >> 2;
        f4v acc[4];
#pragma unroll
        for (int mt = 0; mt < 4; mt++) { f4v z = {0.f, 0.f, 0.f, 0.f}; acc[mt] = z; }
        const ushort_t* Wc = W2p + (size_t)c2 * 16384;
#pragma unroll
        for (int ki = 0; ki < 4; ki++) {
            int kt = khalf * 4 + ki;
            s8v a[4];
#pragma unroll
            for (int mt = 0; mt < 4; mt++)
                a[mt] = *reinterpret_cast<const s8v*>(&bufA[(mt * 16 + l15) * HS + kt * 32 + lq * 8]);
            s8v bb = *reinterpret_cast<const s8v*>(Wc + (((n16 * 8 + kt) * 64 + lane) << 3));
#pragma unroll
            for (int mt = 0; mt < 4; mt++)
                acc[mt] = __builtin_amdgcn_mfma_f32_16x16x32_bf16(a[mt], bb, acc[mt], 0, 0, 0);
        }
        // cross-wave k reduction through f32 scratch (reuses bufB; H1 is dead)
        float* scratch = reinterpret_cast<float*>(bufB);
        if (khalf == 1) {
#pragma unroll
            for (int mt = 0; mt < 4; mt++)
#pragma unroll
                for (int rg = 0; rg < 4; rg++) {
                    int row = mt * 16 + lq * 4 + rg;
                    scratch[row * SCR_S + n16 * 16 + l15] = acc[mt][rg];
                }
        }
        __syncthreads();
        if (khalf == 0) {
            float bias = b2[c2 * 64 + n16 * 16 + l15];
#pragma unroll
            for (int mt = 0; mt < 4; mt++)
#pragma unroll
                for (int rg = 0; rg < 4; rg++) {
                    int row = mt * 16 + lq * 4 + rg;
                    unsigned tok = (unsigned)toks[row];
                    if (tok < (unsigned)N_TOK) {
                        float v = acc[mt][rg] + scratch[row * SCR_S + n16 * 16 + l15] + bias;
                        out[(size_t)tok * 64 + n16 * 16 + l15] = v;
                    }
                }
        }
    }
}

// ---------------------------------------------------------------- launch
extern "C" void kernel_launch(void* const* d_in, const int* in_sizes, int n_in,
                              void* d_out, int out_size, void* d_ws, size_t ws_size,
                              hipStream_t stream) {
    const float* inputs = (const float*)d_in[0];
    const int*   task   = (const int*)d_in[1];
    const int*   cmap   = (const int*)d_in[2];
    const float* W0     = (const float*)d_in[3];
    const float* b0     = (const float*)d_in[4];
    const float* W1     = (const float*)d_in[5];
    const float* b1     = (const float*)d_in[6];
    const float* W2     = (const float*)d_in[7];
    const float* b2     = (const float*)d_in[8];
    float* out = (float*)d_out;

    char* ws = (char*)d_ws;
    int* blockCounts = (int*)(ws + 0);            // 64*16*4 = 4096 B
    int* cur         = (int*)(ws + 4096);         // 16*4 B
    int* nT          = (int*)(ws + 4160);         // 4 B
    int* tileTask    = (int*)(ws + 4352);         // 2064*4 = 8256 B
    int* perm        = (int*)(ws + 12800);        // 132096*4 = 528384 B
    ushort_t* W0p    = (ushort_t*)(ws + 541696);  // 262144 B
    ushort_t* W1p    = (ushort_t*)(ws + 803840);  // 524288 B
    ushort_t* W2p    = (ushort_t*)(ws + 1328128); // 131072 B -> total ~1.46 MB

    prep_kernel<<<224, 256, 0, stream>>>(W0, W1, W2, W0p, W1p, W2p);
    hist_kernel<<<64, 256, 0, stream>>>(task, blockCounts);
    scan_kernel<<<1, 256, 0, stream>>>(blockCounts, cur, tileTask, nT);
    scatter_kernel<<<64, 256, 0, stream>>>(task, cur, perm);
    mlp_kernel<<<NT_MAX, 512, 0, stream>>>(inputs, cmap, b0, b1, b2,
                                           W0p, W1p, W2p, tileTask, nT, perm, out);
}

// Round 3
// 179.290 us; speedup vs baseline: 1.1758x; 1.0524x over previous
//
#include <hip/hip_runtime.h>

#define N_TOK 131072
#define TILE 64
#define NT_MAX 2064          // N_TOK/TILE + 16 tasks worth of padding tiles
#define XS 136               // X row stride (bf16 elems): 128 + 8 pad
#define HS 264               // H row stride (bf16 elems): 256 + 8 pad

typedef __attribute__((ext_vector_type(8))) short s8v;
typedef __attribute__((ext_vector_type(4))) short s4v;
typedef __attribute__((ext_vector_type(4))) float f4v;
typedef unsigned short ushort_t;

__device__ __forceinline__ unsigned short f2bf(float x) {
    union { float f; unsigned u; } v; v.f = x;
    unsigned r = v.u + 0x7fffu + ((v.u >> 16) & 1u);   // RNE
    return (unsigned short)(r >> 16);
}

__device__ __forceinline__ float tanh_fast(float x) {
    float e = __expf(2.0f * x);
    return 1.0f - 2.0f / (e + 1.0f);
}

// ------------------------------------------------- fused prep + hist
// blocks [0,224): repack weights to bf16 MFMA fragments (one 16B write/thread).
// Fragment f: r = (ftile*(K>>5)+kt)*64 + lane; elem j holds W[k][n] with
// n = ftile*16 + (lane&15), k = kt*32 + (lane>>4)*8 + j.  (Used as the A
// operand of Y^T = W^T X^T: A[m=lane&15][k=(lane>>4)*8+j] = W^T[m][k].)
// blocks [224,288): 16-bin histogram of task[], 2048 tokens/block.
__global__ void prep_hist_kernel(const float* __restrict__ W0, const float* __restrict__ W1,
                                 const float* __restrict__ W2,
                                 ushort_t* __restrict__ W0p, ushort_t* __restrict__ W1p,
                                 ushort_t* __restrict__ W2p,
                                 const int* __restrict__ task, int* __restrict__ blockCounts) {
    if (blockIdx.x < 224) {
        int f = blockIdx.x * 256 + threadIdx.x;   // 57344 total fragments
        const float* src; ushort_t* dst; int K, N;
        if (f < 16384)      { src = W0; dst = W0p; K = 128; N = 256; }
        else if (f < 49152) { src = W1; dst = W1p; K = 256; N = 256; f -= 16384; }
        else                { src = W2; dst = W2p; K = 256; N = 64;  f -= 49152; }
        int fpc = (N >> 4) * (K >> 5) * 64;       // fragments per copy
        int c = f / fpc, r = f % fpc;
        int lane = r & 63;
        int kt = (r >> 6) % (K >> 5);
        int ftile = (r >> 6) / (K >> 5);
        int n = ftile * 16 + (lane & 15);
        int kbase = kt * 32 + (lane >> 4) * 8;
        const float* s = src + (size_t)c * K * N + (size_t)kbase * N + n;
        s8v pk;
#pragma unroll
        for (int j = 0; j < 8; j++) pk[j] = (short)f2bf(s[(size_t)j * N]);
        *reinterpret_cast<s8v*>(dst + ((size_t)(c * fpc + r) << 3)) = pk;
    } else {
        __shared__ int cnt[16];
        int t = threadIdx.x;
        int hb = blockIdx.x - 224;
        if (t < 16) cnt[t] = 0;
        __syncthreads();
        int base = hb * 2048 + t;
#pragma unroll
        for (int i = 0; i < 8; i++) atomicAdd(&cnt[task[base + i * 256]], 1);
        __syncthreads();
        if (t < 16) blockCounts[hb * 16 + t] = cnt[t];
    }
}

// ------------------------------------------------- fused scan + scatter
// 64 blocks. Each block redundantly reads all 64x16 counts, computes global
// tile-aligned bases + its own prefix, then scatters its 2048 tokens.
__global__ void sort_kernel(const int* __restrict__ task, const int* __restrict__ blockCounts,
                            int* __restrict__ tileTask, int* __restrict__ nT,
                            int* __restrict__ perm) {
    __shared__ int cntLds[1024];
    __shared__ int total[16], pref[16], rank[16];
    __shared__ int tokBase[16], tbase[17];
    int t = threadIdx.x, b = blockIdx.x;
    for (int i = t; i < 1024; i += 256) cntLds[i] = blockCounts[i];
    if (t < 16) rank[t] = 0;
    __syncthreads();
    if (t < 16) {
        int tot = 0, pf = 0;
#pragma unroll
        for (int bb = 0; bb < 64; bb++) {
            int v = cntLds[bb * 16 + t];
            tot += v;
            if (bb < b) pf += v;
        }
        total[t] = tot; pref[t] = pf;
    }
    __syncthreads();
    if (t == 0) {
        int tok = 0, tile = 0;
        for (int k = 0; k < 16; k++) {
            tokBase[k] = tok;
            tbase[k] = tile;
            int ntk = (total[k] + TILE - 1) / TILE;
            tok += ntk * TILE;
            tile += ntk;
        }
        tbase[16] = tile;
        if (b == 0) nT[0] = tile;
    }
    __syncthreads();
    if (b == 0) {
        for (int i = t; i < NT_MAX; i += 256) {
            int tk = 0;
            if (i < tbase[16]) {
#pragma unroll
                for (int k = 0; k < 16; k++) if (i >= tbase[k]) tk = k;
            }
            tileTask[i] = tk;
        }
    }
    int tk[8], my[8];
#pragma unroll
    for (int i = 0; i < 8; i++) {
        int idx = b * 2048 + i * 256 + t;
        tk[i] = task[idx];
        my[i] = atomicAdd(&rank[tk[i]], 1);
    }
#pragma unroll
    for (int i = 0; i < 8; i++) {
        int idx = b * 2048 + i * 256 + t;
        perm[tokBase[tk[i]] + pref[tk[i]] + my[i]] = idx;
    }
}

// ------------------------------------------------- fused MLP (all-transposed)
// Every layer computes Y^T = W^T @ X^T: weight frag = A operand, activation
// frag = B operand. C-layout: col(lane&15)=token, row(quad*4+rg)=4 consecutive
// output features -> epilogue is ONE ds_write_b64 per (mtile,ntile), and the
// next layer's B-frag read from token-major H is ds_read_b128. 3 barriers/tile.
__launch_bounds__(512, 4)
__global__ void mlp_kernel(const float* __restrict__ x_in,
                           const int* __restrict__ cmap,
                           const float* __restrict__ b0,
                           const float* __restrict__ b1,
                           const float* __restrict__ b2,
                           const ushort_t* __restrict__ W0p,
                           const ushort_t* __restrict__ W1p,
                           const ushort_t* __restrict__ W2p,
                           const int* __restrict__ tileTask,
                           const int* __restrict__ nTp,
                           const int* __restrict__ perm,
                           float* __restrict__ out) {
    __shared__ __align__(16) ushort_t bufA[TILE * HS];   // X (stride XS) then H2 (stride HS)
    __shared__ __align__(16) ushort_t bufB[TILE * HS];   // H1 (stride HS)
    __shared__ int toks[TILE];

    int b = blockIdx.x;
    if (b >= nTp[0]) return;
    int t = threadIdx.x;
    int task = tileTask[b];
    int c0 = cmap[task], c1 = cmap[16 + task], c2 = cmap[32 + task];

    // ---- stage X: gather rows, f32 -> bf16, token-major into bufA (stride XS)
    {
        int r = t >> 3, q = t & 7;            // 8 threads/row, 16 floats each
        int tok = perm[b * TILE + r];         // broadcast among the 8 threads
        if (q == 0) toks[r] = tok;
        float4 v[4];
        if ((unsigned)tok < (unsigned)N_TOK) {
            const float4* src = reinterpret_cast<const float4*>(x_in) + (size_t)tok * 32 + q * 4;
#pragma unroll
            for (int i = 0; i < 4; i++) v[i] = src[i];
        } else {
#pragma unroll
            for (int i = 0; i < 4; i++) v[i] = make_float4(0.f, 0.f, 0.f, 0.f);
        }
        ushort_t* dst = &bufA[r * XS + q * 16];
#pragma unroll
        for (int i = 0; i < 2; i++) {
            float4 va = v[2 * i], vb = v[2 * i + 1];
            s8v pk;
            pk[0] = (short)f2bf(va.x); pk[1] = (short)f2bf(va.y);
            pk[2] = (short)f2bf(va.z); pk[3] = (short)f2bf(va.w);
            pk[4] = (short)f2bf(vb.x); pk[5] = (short)f2bf(vb.y);
            pk[6] = (short)f2bf(vb.z); pk[7] = (short)f2bf(vb.w);
            *reinterpret_cast<s8v*>(dst + i * 8) = pk;
        }
    }
    __syncthreads();

    int w = t >> 6;                 // wave 0..7
    int lane = t & 63;
    int l15 = lane & 15, lq = lane >> 4;

    // ---- Layer 0: H1^T = W0^T X^T. Wave w: feature tiles {2w,2w+1} x 4 token tiles.
    {
        f4v acc[2][4];
#pragma unroll
        for (int mi = 0; mi < 2; mi++)
#pragma unroll
            for (int nt = 0; nt < 4; nt++) { f4v z = {0.f, 0.f, 0.f, 0.f}; acc[mi][nt] = z; }
        const ushort_t* Wc = W0p + (size_t)c0 * 32768;
#pragma unroll
        for (int kt = 0; kt < 4; kt++) {
            s8v xb[4];
#pragma unroll
            for (int nt = 0; nt < 4; nt++)
                xb[nt] = *reinterpret_cast<const s8v*>(&bufA[(nt * 16 + l15) * XS + kt * 32 + lq * 8]);
            s8v wa[2];
#pragma unroll
            for (int mi = 0; mi < 2; mi++)
                wa[mi] = *reinterpret_cast<const s8v*>(Wc + ((((2 * w + mi) * 4 + kt) * 64 + lane) << 3));
#pragma unroll
            for (int mi = 0; mi < 2; mi++)
#pragma unroll
                for (int nt = 0; nt < 4; nt++)
                    acc[mi][nt] = __builtin_amdgcn_mfma_f32_16x16x32_bf16(wa[mi], xb[nt], acc[mi][nt], 0, 0, 0);
        }
#pragma unroll
        for (int mi = 0; mi < 2; mi++) {
            int fbase = (2 * w + mi) * 16 + lq * 4;
            float4 bv = *reinterpret_cast<const float4*>(b0 + c0 * 256 + fbase);
            float br[4] = {bv.x, bv.y, bv.z, bv.w};
#pragma unroll
            for (int nt = 0; nt < 4; nt++) {
                s4v pk;
#pragma unroll
                for (int rg = 0; rg < 4; rg++)
                    pk[rg] = (short)f2bf(tanh_fast(acc[mi][nt][rg] + br[rg]));
                *reinterpret_cast<s4v*>(&bufB[(nt * 16 + l15) * HS + fbase]) = pk;
            }
        }
    }
    __syncthreads();

    // ---- Layer 1: H2^T = W1^T H1^T. (H2 -> bufA; X is dead.)
    {
        f4v acc[2][4];
#pragma unroll
        for (int mi = 0; mi < 2; mi++)
#pragma unroll
            for (int nt = 0; nt < 4; nt++) { f4v z = {0.f, 0.f, 0.f, 0.f}; acc[mi][nt] = z; }
        const ushort_t* Wc = W1p + (size_t)c1 * 65536;
#pragma unroll
        for (int kt = 0; kt < 8; kt++) {
            s8v xb[4];
#pragma unroll
            for (int nt = 0; nt < 4; nt++)
                xb[nt] = *reinterpret_cast<const s8v*>(&bufB[(nt * 16 + l15) * HS + kt * 32 + lq * 8]);
            s8v wa[2];
#pragma unroll
            for (int mi = 0; mi < 2; mi++)
                wa[mi] = *reinterpret_cast<const s8v*>(Wc + ((((2 * w + mi) * 8 + kt) * 64 + lane) << 3));
#pragma unroll
            for (int mi = 0; mi < 2; mi++)
#pragma unroll
                for (int nt = 0; nt < 4; nt++)
                    acc[mi][nt] = __builtin_amdgcn_mfma_f32_16x16x32_bf16(wa[mi], xb[nt], acc[mi][nt], 0, 0, 0);
        }
#pragma unroll
        for (int mi = 0; mi < 2; mi++) {
            int fbase = (2 * w + mi) * 16 + lq * 4;
            float4 bv = *reinterpret_cast<const float4*>(b1 + c1 * 256 + fbase);
            float br[4] = {bv.x, bv.y, bv.z, bv.w};
#pragma unroll
            for (int nt = 0; nt < 4; nt++) {
                s4v pk;
#pragma unroll
                for (int rg = 0; rg < 4; rg++)
                    pk[rg] = (short)f2bf(tanh_fast(acc[mi][nt][rg] + br[rg]));
                *reinterpret_cast<s4v*>(&bufA[(nt * 16 + l15) * HS + fbase]) = pk;
            }
        }
    }
    __syncthreads();

    // ---- Layer 2: O^T = W2^T H2^T. 4 mtiles x 4 ntiles / 8 waves = 2 tiles/wave.
    {
        int mti = w & 3, half = w >> 2;
        f4v acc2[2];
#pragma unroll
        for (int j = 0; j < 2; j++) { f4v z = {0.f, 0.f, 0.f, 0.f}; acc2[j] = z; }
        const ushort_t* Wc = W2p + (size_t)c2 * 16384;
#pragma unroll
        for (int kt = 0; kt < 8; kt++) {
            s8v xb[2];
#pragma unroll
            for (int j = 0; j < 2; j++) {
                int nt = half * 2 + j;
                xb[j] = *reinterpret_cast<const s8v*>(&bufA[(nt * 16 + l15) * HS + kt * 32 + lq * 8]);
            }
            s8v wa = *reinterpret_cast<const s8v*>(Wc + (((mti * 8 + kt) * 64 + lane) << 3));
#pragma unroll
            for (int j = 0; j < 2; j++)
                acc2[j] = __builtin_amdgcn_mfma_f32_16x16x32_bf16(wa, xb[j], acc2[j], 0, 0, 0);
        }
        int fbase = mti * 16 + lq * 4;
        float4 bv = *reinterpret_cast<const float4*>(b2 + c2 * 64 + fbase);
#pragma unroll
        for (int j = 0; j < 2; j++) {
            int row = (half * 2 + j) * 16 + l15;
            int tok = toks[row];
            if ((unsigned)tok < (unsigned)N_TOK) {
                float4 o;
                o.x = acc2[j][0] + bv.x; o.y = acc2[j][1] + bv.y;
                o.z = acc2[j][2] + bv.z; o.w = acc2[j][3] + bv.w;
                *reinterpret_cast<float4*>(out + (size_t)tok * 64 + fbase) = o;
            }
        }
    }
}

// ---------------------------------------------------------------- launch
extern "C" void kernel_launch(void* const* d_in, const int* in_sizes, int n_in,
                              void* d_out, int out_size, void* d_ws, size_t ws_size,
                              hipStream_t stream) {
    const float* inputs = (const float*)d_in[0];
    const int*   task   = (const int*)d_in[1];
    const int*   cmap   = (const int*)d_in[2];
    const float* W0     = (const float*)d_in[3];
    const float* b0     = (const float*)d_in[4];
    const float* W1     = (const float*)d_in[5];
    const float* b1     = (const float*)d_in[6];
    const float* W2     = (const float*)d_in[7];
    const float* b2     = (const float*)d_in[8];
    float* out = (float*)d_out;

    char* ws = (char*)d_ws;
    int* blockCounts = (int*)(ws + 0);            // 64*16*4 = 4096 B
    int* nT          = (int*)(ws + 4096);         // 4 B
    int* tileTask    = (int*)(ws + 4160);         // 2064*4 = 8256 B
    int* perm        = (int*)(ws + 12416);        // 132096*4 = 528384 B
    ushort_t* W0p    = (ushort_t*)(ws + 540800);  // 262144 B
    ushort_t* W1p    = (ushort_t*)(ws + 802944);  // 524288 B
    ushort_t* W2p    = (ushort_t*)(ws + 1327232); // 131072 B -> total ~1.46 MB

    prep_hist_kernel<<<288, 256, 0, stream>>>(W0, W1, W2, W0p, W1p, W2p, task, blockCounts);
    sort_kernel<<<64, 256, 0, stream>>>(task, blockCounts, tileTask, nT, perm);
    mlp_kernel<<<NT_MAX, 512, 0, stream>>>(inputs, cmap, b0, b1, b2,
                                           W0p, W1p, W2p, tileTask, nT, perm, out);
}